// Round 6
// baseline (5681.102 us; speedup 1.0000x reference)
//
#include <hip/hip_runtime.h>
#include <math.h>

#define NN 500000
#define NE 16000000
#define ST 62                    // dst supertiles: dst>>13 (8192 dsts)
#define STB 8192
#define NC 62                    // src cells: src>>13 (8192 srcs = 32KB z window)
#define SB 8192                  // LDS staging batch (edges)
#define PBA 16384                // histA edges per block
#define NBA ((NE + PBA - 1) / PBA)   // 977
#define CHUNKS 8
#define GRID_ST8 (8 * 64)        // swizzle: x=bid&7, y=bid>>3, st=x+8*(y&7), chunk=y>>3

// ---------- phase A1: histogram by dst supertile ----------
__global__ __launch_bounds__(256) void histA(const int4* __restrict__ dst4,
                                             int* __restrict__ bcntA) {
    __shared__ int lh[ST];
    if (threadIdx.x < ST) lh[threadIdx.x] = 0;
    __syncthreads();
    long base4 = (long)blockIdx.x * (PBA / 4);
    for (int k = 0; k < PBA / 4; k += 256) {
        long i4 = base4 + k + threadIdx.x;
        if (i4 < NE / 4) {
            int4 d = dst4[i4];
            atomicAdd(&lh[d.x >> 13], 1);
            atomicAdd(&lh[d.y >> 13], 1);
            atomicAdd(&lh[d.z >> 13], 1);
            atomicAdd(&lh[d.w >> 13], 1);
        }
    }
    __syncthreads();
    if (threadIdx.x < ST) {
        int c = lh[threadIdx.x];
        if (c) atomicAdd(&bcntA[threadIdx.x], c);
    }
}

// ---------- phase A2: scan 62 counts (one wave) ----------
__global__ void scanA(const int* __restrict__ bcntA, int* __restrict__ regBase,
                      int* __restrict__ curA) {
    int i = threadIdx.x;                          // 64 threads
    int v = (i < ST) ? bcntA[i] : 0;
    int incl = v;
    for (int off = 1; off < 64; off <<= 1) {
        int t = __shfl_up(incl, off);
        if (i >= off) incl += t;
    }
    if (i < ST) { regBase[i] = incl - v; curA[i] = incl - v; }
    if (i == 63) regBase[ST] = incl;
}

// ---------- phase A3: LDS-staged scatter by dst supertile ----------
// tmp[pos] = (dst&8191)<<19 | src ; writes are coalesced per-key runs (~528B)
__global__ __launch_bounds__(512) void scatterA(const int* __restrict__ src,
                                                const int* __restrict__ dst,
                                                int* __restrict__ curA,
                                                unsigned* __restrict__ tmp) {
    __shared__ unsigned eds[SB];
    __shared__ unsigned char kds[SB];
    __shared__ unsigned outb[SB];
    __shared__ int lh[64], lb[64], gb[64];
    long beg = (long)blockIdx.x * (NE / 512);     // 31250 exact
    long end = beg + NE / 512;
    for (long pos = beg; pos < end; pos += SB) {
        int n = (int)((end - pos < SB) ? (end - pos) : SB);
        for (int i = threadIdx.x; i < n; i += 512) {
            int d = dst[pos + i];
            int s = src[pos + i];
            eds[i] = ((unsigned)(d & 8191) << 19) | (unsigned)s;
            kds[i] = (unsigned char)(d >> 13);
        }
        if (threadIdx.x < 64) lh[threadIdx.x] = 0;
        __syncthreads();
        for (int i = threadIdx.x; i < n; i += 512) atomicAdd(&lh[kds[i]], 1);
        __syncthreads();
        if (threadIdx.x < 64) {
            int v = lh[threadIdx.x];
            int incl = v;
            for (int off = 1; off < 64; off <<= 1) {
                int t = __shfl_up(incl, off);
                if (threadIdx.x >= off) incl += t;
            }
            int ex = incl - v;
            lb[threadIdx.x] = ex;
            gb[threadIdx.x] = (threadIdx.x < ST && v) ? atomicAdd(&curA[threadIdx.x], v) : 0;
            lh[threadIdx.x] = ex;                 // local cursor
        }
        __syncthreads();
        for (int i = threadIdx.x; i < n; i += 512) {
            int p = atomicAdd(&lh[kds[i]], 1);
            outb[p] = eds[i];
        }
        __syncthreads();
        for (int i = threadIdx.x; i < n; i += 512) {
            int c = 0;                             // largest c with lb[c] <= i
            for (int step = 32; step; step >>= 1)
                if (c + step < 64 && lb[c + step] <= i) c += step;
            tmp[gb[c] + (i - lb[c])] = outb[i];
        }
        __syncthreads();
    }
}

// ---------- phase B1: per-(supertile, src-cell) histogram + node degree ----------
__global__ __launch_bounds__(512) void histB(const unsigned* __restrict__ tmp,
                                             const int* __restrict__ regBase,
                                             int* __restrict__ cellCnt,
                                             int* __restrict__ deg) {
    __shared__ int gh[64];
    __shared__ int dh[STB];
    int x = blockIdx.x & 7, y = blockIdx.x >> 3;
    int st = x + 8 * (y & 7), sb = y >> 3;
    if (st >= ST) return;
    int base = regBase[st];
    int len = regBase[st + 1] - base;
    int beg = base + (int)((long)len * sb / 8);
    int end = base + (int)((long)len * (sb + 1) / 8);
    if (threadIdx.x < 64) gh[threadIdx.x] = 0;
    for (int i = threadIdx.x; i < STB; i += 512) dh[i] = 0;
    __syncthreads();
    for (int i = beg + threadIdx.x; i < end; i += 512) {
        unsigned e = tmp[i];
        atomicAdd(&gh[(e & 0x7FFFFu) >> 13], 1);
        atomicAdd(&dh[e >> 19], 1);
    }
    __syncthreads();
    if (threadIdx.x < NC) {
        int c = gh[threadIdx.x];
        if (c) atomicAdd(&cellCnt[st * NC + threadIdx.x], c);
    }
    for (int i = threadIdx.x; i < STB; i += 512) {
        int c = dh[i];
        if (c) atomicAdd(&deg[st * STB + i], c);
    }
}

// ---------- phase B2: per-supertile scan of 62 cell counts (one wave) ----------
__global__ void scanB(const int* __restrict__ regBase, const int* __restrict__ cellCnt,
                      int* __restrict__ cellBase, int* __restrict__ cellCur) {
    int st = blockIdx.x;
    int i = threadIdx.x;                          // 64 threads
    int v = (i < NC) ? cellCnt[st * NC + i] : 0;
    int incl = v;
    for (int off = 1; off < 64; off <<= 1) {
        int t = __shfl_up(incl, off);
        if (i >= off) incl += t;
    }
    int ex = regBase[st] + incl - v;
    if (i < NC) { cellBase[st * NC + i] = ex; cellCur[st * NC + i] = ex; }
}

// ---------- phase B3: LDS-staged scatter by src cell within supertile ----------
__global__ __launch_bounds__(512) void scatterB(const unsigned* __restrict__ tmp,
                                                const int* __restrict__ regBase,
                                                int* __restrict__ cellCur,
                                                unsigned* __restrict__ ebuf) {
    __shared__ unsigned eds[SB];
    __shared__ unsigned outb[SB];
    __shared__ int lh[64], lb[64], gb[64];
    int x = blockIdx.x & 7, y = blockIdx.x >> 3;
    int st = x + 8 * (y & 7), sb = y >> 3;
    if (st >= ST) return;
    int base = regBase[st];
    int len = regBase[st + 1] - base;
    int beg = base + (int)((long)len * sb / 8);
    int end = base + (int)((long)len * (sb + 1) / 8);
    for (int pos = beg; pos < end; pos += SB) {
        int n = (end - pos < SB) ? (end - pos) : SB;
        for (int i = threadIdx.x; i < n; i += 512) eds[i] = tmp[pos + i];
        if (threadIdx.x < 64) lh[threadIdx.x] = 0;
        __syncthreads();
        for (int i = threadIdx.x; i < n; i += 512)
            atomicAdd(&lh[(eds[i] & 0x7FFFFu) >> 13], 1);
        __syncthreads();
        if (threadIdx.x < 64) {
            int v = lh[threadIdx.x];
            int incl = v;
            for (int off = 1; off < 64; off <<= 1) {
                int t = __shfl_up(incl, off);
                if (threadIdx.x >= off) incl += t;
            }
            int ex = incl - v;
            lb[threadIdx.x] = ex;
            gb[threadIdx.x] = (threadIdx.x < NC && v)
                              ? atomicAdd(&cellCur[st * NC + threadIdx.x], v) : 0;
            lh[threadIdx.x] = ex;
        }
        __syncthreads();
        for (int i = threadIdx.x; i < n; i += 512) {
            unsigned e = eds[i];
            int p = atomicAdd(&lh[(e & 0x7FFFFu) >> 13], 1);
            outb[p] = e;
        }
        __syncthreads();
        for (int i = threadIdx.x; i < n; i += 512) {
            int c = 0;
            for (int step = 32; step; step >>= 1)
                if (c + step < 64 && lb[c + step] <= i) c += step;
            ebuf[gb[c] + (i - lb[c])] = outb[i];
        }
        __syncthreads();
    }
}

// ---------- dis + z0 ----------
__global__ void disz(const int* __restrict__ deg, const float* __restrict__ x0,
                     float* __restrict__ dis, float* __restrict__ z0) {
    int v = blockIdx.x * 256 + threadIdx.x;
    if (v < NN) {
        float f = rsqrtf((float)(deg[v] + 1));     // +1 self loop
        dis[v] = f;
        z0[v] = x0[v] * f;
    }
}

// ---------- per-layer: accumulate with LDS z-window (no divergent global loads) ----------
__global__ __launch_bounds__(512) void accum(const unsigned* __restrict__ ebuf,
                                             const int* __restrict__ regBase,
                                             const int* __restrict__ cellBase,
                                             const float* __restrict__ zin,
                                             float* __restrict__ partial) {
    __shared__ float h[STB];                       // 32 KB dst tile
    __shared__ float win[8192];                    // 32 KB src z-window
    int x = blockIdx.x & 7, y = blockIdx.x >> 3;
    int st = x + 8 * (y & 7), ck = y >> 3;         // ck in [0,8)
    if (st >= ST) return;
    for (int j = threadIdx.x; j < STB; j += 512) h[j] = 0.f;
    int c0 = ck * NC / CHUNKS, c1 = (ck + 1) * NC / CHUNKS;
    for (int cell = c0; cell < c1; cell++) {
        int wbase = cell << 13;
        int wn = NN - wbase; if (wn > 8192) wn = 8192;
        __syncthreads();                           // win not in use beyond here
        for (int j = threadIdx.x; j < wn; j += 512) win[j] = zin[wbase + j];
        __syncthreads();
        int beg = cellBase[st * NC + cell];
        int end = (cell == NC - 1) ? regBase[st + 1] : cellBase[st * NC + cell + 1];
        int beg4 = (beg + 3) & ~3; if (beg4 > end) beg4 = end;
        int end4 = end & ~3;       if (end4 < beg4) end4 = beg4;
        for (int i = beg + threadIdx.x; i < beg4; i += 512) {
            unsigned e = ebuf[i];
            atomicAdd(&h[e >> 19], win[e & 8191u]);
        }
        const uint4* eb4 = (const uint4*)ebuf;
        for (int i4 = beg4 / 4 + threadIdx.x; i4 < end4 / 4; i4 += 512) {
            uint4 e = eb4[i4];
            atomicAdd(&h[e.x >> 19], win[e.x & 8191u]);
            atomicAdd(&h[e.y >> 19], win[e.y & 8191u]);
            atomicAdd(&h[e.z >> 19], win[e.z & 8191u]);
            atomicAdd(&h[e.w >> 19], win[e.w & 8191u]);
        }
        for (int i = end4 + threadIdx.x; i < end; i += 512) {
            unsigned e = ebuf[i];
            atomicAdd(&h[e >> 19], win[e & 8191u]);
        }
    }
    __syncthreads();
    float* pt = partial + (size_t)ck * (ST * STB) + st * STB;
    for (int j = threadIdx.x; j < STB; j += 512) pt[j] = h[j];
}

// ---------- per-layer: finalize (sum partials, self-loop, activation) ----------
// act: 0=none 1=relu 2=leaky(0.01) 3=sigmoid 4=final(n*sigmoid -> int)
__global__ __launch_bounds__(256) void finalize(const float* __restrict__ partial,
                                                const float* __restrict__ zin,
                                                const float* __restrict__ dis,
                                                const float* __restrict__ x0,
                                                const float* __restrict__ w,
                                                int li, int act,
                                                float* __restrict__ zout,
                                                int* __restrict__ out) {
    int v = blockIdx.x * 256 + threadIdx.x;
    if (v >= NN) return;
    float hv = 0.f;
    #pragma unroll
    for (int c = 0; c < CHUNKS; c++) hv += partial[(size_t)c * (ST * STB) + v];
    float s = hv + zin[v];                          // + self loop
    float hh = dis[v] * s;
    float comb = 0.7f * hh + 0.3f * x0[v];
    float y = comb * w[li];
    if (act == 4) {
        float sg = 1.f / (1.f + expf(-y));
        out[v] = (int)(500000.f * sg);
        return;
    }
    float r;
    if (act == 0)      r = y;
    else if (act == 1) r = fmaxf(y, 0.f);
    else if (act == 2) r = (y > 0.f) ? y : 0.01f * y;
    else               r = 1.f / (1.f + expf(-y));  // sigmoid
    zout[v] = dis[v] * r;
}

// ---------- launch ----------
extern "C" void kernel_launch(void* const* d_in, const int* in_sizes, int n_in,
                              void* d_out, int out_size, void* d_ws, size_t ws_size,
                              hipStream_t stream) {
    const float* x0  = (const float*)d_in[0];
    const float* w   = (const float*)d_in[1];
    const int*   adj = (const int*)d_in[2];          // int32 (jax demotes int64)
    const int*   src = adj;
    const int*   dst = adj + NE;
    int* out = (int*)d_out;

    uintptr_t p = (uintptr_t)d_ws;
    auto alloc = [&](size_t bytes) -> void* {
        p = (p + 255) & ~(uintptr_t)255;
        void* r = (void*)p;
        p += bytes;
        return r;
    };
    float*    dis      = (float*)alloc((size_t)NN * 4);
    float*    z0       = (float*)alloc((size_t)NN * 4);
    float*    z1       = (float*)alloc((size_t)NN * 4);
    int*      deg      = (int*)alloc((size_t)ST * STB * 4);
    float*    partial  = (float*)alloc((size_t)CHUNKS * ST * STB * 4);
    int*      bcntA    = (int*)alloc((size_t)ST * 4);
    int*      regBase  = (int*)alloc((size_t)(ST + 1) * 4);
    int*      curA     = (int*)alloc((size_t)ST * 4);
    int*      cellCnt  = (int*)alloc((size_t)ST * NC * 4);
    int*      cellBase = (int*)alloc((size_t)ST * NC * 4);
    int*      cellCur  = (int*)alloc((size_t)ST * NC * 4);
    unsigned* tmp      = (unsigned*)alloc((size_t)NE * 4);
    unsigned* ebuf     = (unsigned*)alloc((size_t)NE * 4);
    (void)ws_size;

    hipMemsetAsync(bcntA, 0, (size_t)ST * 4, stream);
    hipMemsetAsync(cellCnt, 0, (size_t)ST * NC * 4, stream);
    hipMemsetAsync(deg, 0, (size_t)ST * STB * 4, stream);

    histA<<<NBA, 256, 0, stream>>>((const int4*)dst, bcntA);
    scanA<<<1, 64, 0, stream>>>(bcntA, regBase, curA);
    scatterA<<<512, 512, 0, stream>>>(src, dst, curA, tmp);
    histB<<<GRID_ST8, 512, 0, stream>>>(tmp, regBase, cellCnt, deg);
    scanB<<<ST, 64, 0, stream>>>(regBase, cellCnt, cellBase, cellCur);
    scatterB<<<GRID_ST8, 512, 0, stream>>>(tmp, regBase, cellCur, ebuf);
    disz<<<(NN + 255) / 256, 256, 0, stream>>>(deg, x0, dis, z0);

    float* zbuf[2] = {z0, z1};
    for (int i = 0; i < 49; i++) {
        int act;
        if (i == 0)            act = 0;
        else if (i == 48)      act = 4;
        else if (i % 10 == 1)  act = 2;                 // leaky {1,11,21,31,41}
        else if (i % 10 == 4)  act = 3;                 // sigmoid {4,14,24,34,44}
        else                   act = 1;                 // relu
        accum<<<GRID_ST8, 512, 0, stream>>>(ebuf, regBase, cellBase, zbuf[i & 1], partial);
        finalize<<<(NN + 255) / 256, 256, 0, stream>>>(partial, zbuf[i & 1], dis, x0, w,
                                                       i, act, zbuf[(i + 1) & 1], out);
    }
}

// Round 7
// 5549.192 us; speedup vs baseline: 1.0238x; 1.0238x over previous
//
#include <hip/hip_runtime.h>
#include <math.h>

#define NN 500000
#define NE 16000000
#define ST 62                    // dst supertiles: dst>>13 (8192 dsts)
#define STB 8192
#define NC 62                    // src cells: src>>13 (8192 srcs = 32KB z window)
#define SB 8192                  // LDS staging batch (edges)
#define PBA 16384                // histA edges per block
#define NBA ((NE + PBA - 1) / PBA)   // 977
#define CHUNKS 8
#define GRID_ST8 (8 * 64)        // swizzle: x=bid&7, y=bid>>3, st=x+8*(y&7), chunk=y>>3

// ---------- phase A1: histogram by dst supertile ----------
__global__ __launch_bounds__(256) void histA(const int4* __restrict__ dst4,
                                             int* __restrict__ bcntA) {
    __shared__ int lh[ST];
    if (threadIdx.x < ST) lh[threadIdx.x] = 0;
    __syncthreads();
    long base4 = (long)blockIdx.x * (PBA / 4);
    for (int k = 0; k < PBA / 4; k += 256) {
        long i4 = base4 + k + threadIdx.x;
        if (i4 < NE / 4) {
            int4 d = dst4[i4];
            atomicAdd(&lh[d.x >> 13], 1);
            atomicAdd(&lh[d.y >> 13], 1);
            atomicAdd(&lh[d.z >> 13], 1);
            atomicAdd(&lh[d.w >> 13], 1);
        }
    }
    __syncthreads();
    if (threadIdx.x < ST) {
        int c = lh[threadIdx.x];
        if (c) atomicAdd(&bcntA[threadIdx.x], c);
    }
}

// ---------- phase A2: scan 62 counts (one wave) ----------
__global__ void scanA(const int* __restrict__ bcntA, int* __restrict__ regBase,
                      int* __restrict__ curA) {
    int i = threadIdx.x;                          // 64 threads
    int v = (i < ST) ? bcntA[i] : 0;
    int incl = v;
    for (int off = 1; off < 64; off <<= 1) {
        int t = __shfl_up(incl, off);
        if (i >= off) incl += t;
    }
    if (i < ST) { regBase[i] = incl - v; curA[i] = incl - v; }
    if (i == 63) regBase[ST] = incl;
}

// ---------- phase A3: LDS-staged scatter by dst supertile ----------
// tmp[pos] = (dst&8191)<<19 | src ; writes are coalesced per-key runs
__global__ __launch_bounds__(512) void scatterA(const int* __restrict__ src,
                                                const int* __restrict__ dst,
                                                int* __restrict__ curA,
                                                unsigned* __restrict__ tmp) {
    __shared__ unsigned eds[SB];
    __shared__ unsigned char kds[SB];
    __shared__ unsigned outb[SB];
    __shared__ int lh[64], lb[64], gb[64];
    long beg = (long)blockIdx.x * (NE / 512);     // 31250 exact
    long end = beg + NE / 512;
    for (long pos = beg; pos < end; pos += SB) {
        int n = (int)((end - pos < SB) ? (end - pos) : SB);
        for (int i = threadIdx.x; i < n; i += 512) {
            int d = dst[pos + i];
            int s = src[pos + i];
            eds[i] = ((unsigned)(d & 8191) << 19) | (unsigned)s;
            kds[i] = (unsigned char)(d >> 13);
        }
        if (threadIdx.x < 64) lh[threadIdx.x] = 0;
        __syncthreads();
        for (int i = threadIdx.x; i < n; i += 512) atomicAdd(&lh[kds[i]], 1);
        __syncthreads();
        if (threadIdx.x < 64) {
            int v = lh[threadIdx.x];
            int incl = v;
            for (int off = 1; off < 64; off <<= 1) {
                int t = __shfl_up(incl, off);
                if (threadIdx.x >= off) incl += t;
            }
            int ex = incl - v;
            lb[threadIdx.x] = ex;
            gb[threadIdx.x] = (threadIdx.x < ST && v) ? atomicAdd(&curA[threadIdx.x], v) : 0;
            lh[threadIdx.x] = ex;                 // local cursor
        }
        __syncthreads();
        for (int i = threadIdx.x; i < n; i += 512) {
            int p = atomicAdd(&lh[kds[i]], 1);
            outb[p] = eds[i];
        }
        __syncthreads();
        for (int i = threadIdx.x; i < n; i += 512) {
            int c = 0;                             // largest c with lb[c] <= i
            for (int step = 32; step; step >>= 1)
                if (c + step < 64 && lb[c + step] <= i) c += step;
            tmp[gb[c] + (i - lb[c])] = outb[i];
        }
        __syncthreads();
    }
}

// ---------- phase B1: per-(supertile, src-cell) histogram + node degree ----------
__global__ __launch_bounds__(512) void histB(const unsigned* __restrict__ tmp,
                                             const int* __restrict__ regBase,
                                             int* __restrict__ cellCnt,
                                             int* __restrict__ deg) {
    __shared__ int gh[64];
    __shared__ int dh[STB];
    int x = blockIdx.x & 7, y = blockIdx.x >> 3;
    int st = x + 8 * (y & 7), sb = y >> 3;
    if (st >= ST) return;
    int base = regBase[st];
    int len = regBase[st + 1] - base;
    int beg = base + (int)((long)len * sb / 8);
    int end = base + (int)((long)len * (sb + 1) / 8);
    if (threadIdx.x < 64) gh[threadIdx.x] = 0;
    for (int i = threadIdx.x; i < STB; i += 512) dh[i] = 0;
    __syncthreads();
    for (int i = beg + threadIdx.x; i < end; i += 512) {
        unsigned e = tmp[i];
        atomicAdd(&gh[(e & 0x7FFFFu) >> 13], 1);
        atomicAdd(&dh[e >> 19], 1);
    }
    __syncthreads();
    if (threadIdx.x < NC) {
        int c = gh[threadIdx.x];
        if (c) atomicAdd(&cellCnt[st * NC + threadIdx.x], c);
    }
    for (int i = threadIdx.x; i < STB; i += 512) {
        int c = dh[i];
        if (c) atomicAdd(&deg[st * STB + i], c);
    }
}

// ---------- phase B2: per-supertile scan of 62 cell counts (one wave) ----------
__global__ void scanB(const int* __restrict__ regBase, const int* __restrict__ cellCnt,
                      int* __restrict__ cellBase, int* __restrict__ cellCur) {
    int st = blockIdx.x;
    int i = threadIdx.x;                          // 64 threads
    int v = (i < NC) ? cellCnt[st * NC + i] : 0;
    int incl = v;
    for (int off = 1; off < 64; off <<= 1) {
        int t = __shfl_up(incl, off);
        if (i >= off) incl += t;
    }
    int ex = regBase[st] + incl - v;
    if (i < NC) { cellBase[st * NC + i] = ex; cellCur[st * NC + i] = ex; }
}

// ---------- phase B3: LDS-staged scatter by src cell within supertile ----------
__global__ __launch_bounds__(512) void scatterB(const unsigned* __restrict__ tmp,
                                                const int* __restrict__ regBase,
                                                int* __restrict__ cellCur,
                                                unsigned* __restrict__ ebuf) {
    __shared__ unsigned eds[SB];
    __shared__ unsigned outb[SB];
    __shared__ int lh[64], lb[64], gb[64];
    int x = blockIdx.x & 7, y = blockIdx.x >> 3;
    int st = x + 8 * (y & 7), sb = y >> 3;
    if (st >= ST) return;
    int base = regBase[st];
    int len = regBase[st + 1] - base;
    int beg = base + (int)((long)len * sb / 8);
    int end = base + (int)((long)len * (sb + 1) / 8);
    for (int pos = beg; pos < end; pos += SB) {
        int n = (end - pos < SB) ? (end - pos) : SB;
        for (int i = threadIdx.x; i < n; i += 512) eds[i] = tmp[pos + i];
        if (threadIdx.x < 64) lh[threadIdx.x] = 0;
        __syncthreads();
        for (int i = threadIdx.x; i < n; i += 512)
            atomicAdd(&lh[(eds[i] & 0x7FFFFu) >> 13], 1);
        __syncthreads();
        if (threadIdx.x < 64) {
            int v = lh[threadIdx.x];
            int incl = v;
            for (int off = 1; off < 64; off <<= 1) {
                int t = __shfl_up(incl, off);
                if (threadIdx.x >= off) incl += t;
            }
            int ex = incl - v;
            lb[threadIdx.x] = ex;
            gb[threadIdx.x] = (threadIdx.x < NC && v)
                              ? atomicAdd(&cellCur[st * NC + threadIdx.x], v) : 0;
            lh[threadIdx.x] = ex;
        }
        __syncthreads();
        for (int i = threadIdx.x; i < n; i += 512) {
            unsigned e = eds[i];
            int p = atomicAdd(&lh[(e & 0x7FFFFu) >> 13], 1);
            outb[p] = e;
        }
        __syncthreads();
        for (int i = threadIdx.x; i < n; i += 512) {
            int c = 0;
            for (int step = 32; step; step >>= 1)
                if (c + step < 64 && lb[c + step] <= i) c += step;
            ebuf[gb[c] + (i - lb[c])] = outb[i];
        }
        __syncthreads();
    }
}

// ---------- dis + z0 ----------
__global__ void disz(const int* __restrict__ deg, const float* __restrict__ x0,
                     float* __restrict__ dis, float* __restrict__ z0) {
    int v = blockIdx.x * 256 + threadIdx.x;
    if (v < NN) {
        float f = rsqrtf((float)(deg[v] + 1));     // +1 self loop
        dis[v] = f;
        z0[v] = x0[v] * f;
    }
}

// ---------- per-layer: accumulate; 1024 thr, reg-prefetched z-window ----------
// NOTE: window float4 prefetch reads up to 62*8192 floats from zin; zin buffers
// are followed by other ws arrays, so OOB-window reads are safe and unused.
__global__ __launch_bounds__(1024, 8) void accum(const unsigned* __restrict__ ebuf,
                                                 const int* __restrict__ regBase,
                                                 const int* __restrict__ cellBase,
                                                 const float* __restrict__ zin,
                                                 float* __restrict__ partial) {
    __shared__ float h[STB];                       // 32 KB dst tile
    __shared__ float win[8192];                    // 32 KB src z-window
    int x = blockIdx.x & 7, y = blockIdx.x >> 3;
    int st = x + 8 * (y & 7), ck = y >> 3;         // ck in [0,8)
    if (st >= ST) return;
    for (int j = threadIdx.x; j < STB; j += 1024) h[j] = 0.f;
    int c0 = ck * NC / CHUNKS, c1 = (ck + 1) * NC / CHUNKS;
    // prefetch first window slice into regs (8192 floats = 2048 float4, 2/thread)
    float4 pf0, pf1;
    {
        const float4* z4 = (const float4*)(zin + (c0 << 13));
        pf0 = z4[threadIdx.x];
        pf1 = z4[threadIdx.x + 1024];
    }
    for (int cell = c0; cell < c1; cell++) {
        __syncthreads();                           // h-init / prev-cell win reads done
        ((float4*)win)[threadIdx.x] = pf0;
        ((float4*)win)[threadIdx.x + 1024] = pf1;
        __syncthreads();                           // win ready
        if (cell + 1 < c1) {                       // overlap next staging w/ edges
            const float4* z4 = (const float4*)(zin + ((cell + 1) << 13));
            pf0 = z4[threadIdx.x];
            pf1 = z4[threadIdx.x + 1024];
        }
        int beg = cellBase[st * NC + cell];
        int end = (cell == NC - 1) ? regBase[st + 1] : cellBase[st * NC + cell + 1];
        int beg4 = (beg + 3) & ~3; if (beg4 > end) beg4 = end;
        int end4 = end & ~3;       if (end4 < beg4) end4 = beg4;
        for (int i = beg + threadIdx.x; i < beg4; i += 1024) {
            unsigned e = ebuf[i];
            atomicAdd(&h[e >> 19], win[e & 8191u]);
        }
        const uint4* eb4 = (const uint4*)ebuf;
        for (int i4 = beg4 / 4 + threadIdx.x; i4 < end4 / 4; i4 += 1024) {
            uint4 e = eb4[i4];
            atomicAdd(&h[e.x >> 19], win[e.x & 8191u]);
            atomicAdd(&h[e.y >> 19], win[e.y & 8191u]);
            atomicAdd(&h[e.z >> 19], win[e.z & 8191u]);
            atomicAdd(&h[e.w >> 19], win[e.w & 8191u]);
        }
        for (int i = end4 + threadIdx.x; i < end; i += 1024) {
            unsigned e = ebuf[i];
            atomicAdd(&h[e >> 19], win[e & 8191u]);
        }
    }
    __syncthreads();
    float* pt = partial + (size_t)ck * (ST * STB) + st * STB;
    for (int j = threadIdx.x; j < STB; j += 1024) pt[j] = h[j];
}

// ---------- per-layer: finalize (sum partials, self-loop, activation) ----------
// act: 0=none 1=relu 2=leaky(0.01) 3=sigmoid 4=final(n*sigmoid -> int)
__global__ __launch_bounds__(256) void finalize(const float* __restrict__ partial,
                                                const float* __restrict__ zin,
                                                const float* __restrict__ dis,
                                                const float* __restrict__ x0,
                                                const float* __restrict__ w,
                                                int li, int act,
                                                float* __restrict__ zout,
                                                int* __restrict__ out) {
    int v = blockIdx.x * 256 + threadIdx.x;
    if (v >= NN) return;
    float hv = 0.f;
    #pragma unroll
    for (int c = 0; c < CHUNKS; c++) hv += partial[(size_t)c * (ST * STB) + v];
    float s = hv + zin[v];                          // + self loop
    float hh = dis[v] * s;
    float comb = 0.7f * hh + 0.3f * x0[v];
    float y = comb * w[li];
    if (act == 4) {
        float sg = 1.f / (1.f + expf(-y));
        out[v] = (int)(500000.f * sg);
        return;
    }
    float r;
    if (act == 0)      r = y;
    else if (act == 1) r = fmaxf(y, 0.f);
    else if (act == 2) r = (y > 0.f) ? y : 0.01f * y;
    else               r = 1.f / (1.f + expf(-y));  // sigmoid
    zout[v] = dis[v] * r;
}

// ---------- launch ----------
extern "C" void kernel_launch(void* const* d_in, const int* in_sizes, int n_in,
                              void* d_out, int out_size, void* d_ws, size_t ws_size,
                              hipStream_t stream) {
    const float* x0  = (const float*)d_in[0];
    const float* w   = (const float*)d_in[1];
    const int*   adj = (const int*)d_in[2];          // int32 (jax demotes int64)
    const int*   src = adj;
    const int*   dst = adj + NE;
    int* out = (int*)d_out;

    uintptr_t p = (uintptr_t)d_ws;
    auto alloc = [&](size_t bytes) -> void* {
        p = (p + 255) & ~(uintptr_t)255;
        void* r = (void*)p;
        p += bytes;
        return r;
    };
    float*    dis      = (float*)alloc((size_t)NN * 4);
    float*    z0       = (float*)alloc((size_t)NN * 4);
    float*    z1       = (float*)alloc((size_t)NN * 4);
    int*      deg      = (int*)alloc((size_t)ST * STB * 4);
    float*    partial  = (float*)alloc((size_t)CHUNKS * ST * STB * 4);
    int*      bcntA    = (int*)alloc((size_t)ST * 4);
    int*      regBase  = (int*)alloc((size_t)(ST + 1) * 4);
    int*      curA     = (int*)alloc((size_t)ST * 4);
    int*      cellCnt  = (int*)alloc((size_t)ST * NC * 4);
    int*      cellBase = (int*)alloc((size_t)ST * NC * 4);
    int*      cellCur  = (int*)alloc((size_t)ST * NC * 4);
    unsigned* tmp      = (unsigned*)alloc((size_t)NE * 4);
    unsigned* ebuf     = (unsigned*)alloc((size_t)NE * 4);
    (void)ws_size;

    hipMemsetAsync(bcntA, 0, (size_t)ST * 4, stream);
    hipMemsetAsync(cellCnt, 0, (size_t)ST * NC * 4, stream);
    hipMemsetAsync(deg, 0, (size_t)ST * STB * 4, stream);

    histA<<<NBA, 256, 0, stream>>>((const int4*)dst, bcntA);
    scanA<<<1, 64, 0, stream>>>(bcntA, regBase, curA);
    scatterA<<<512, 512, 0, stream>>>(src, dst, curA, tmp);
    histB<<<GRID_ST8, 512, 0, stream>>>(tmp, regBase, cellCnt, deg);
    scanB<<<ST, 64, 0, stream>>>(regBase, cellCnt, cellBase, cellCur);
    scatterB<<<GRID_ST8, 512, 0, stream>>>(tmp, regBase, cellCur, ebuf);
    disz<<<(NN + 255) / 256, 256, 0, stream>>>(deg, x0, dis, z0);

    float* zbuf[2] = {z0, z1};
    for (int i = 0; i < 49; i++) {
        int act;
        if (i == 0)            act = 0;
        else if (i == 48)      act = 4;
        else if (i % 10 == 1)  act = 2;                 // leaky {1,11,21,31,41}
        else if (i % 10 == 4)  act = 3;                 // sigmoid {4,14,24,34,44}
        else                   act = 1;                 // relu
        accum<<<GRID_ST8, 1024, 0, stream>>>(ebuf, regBase, cellBase, zbuf[i & 1], partial);
        finalize<<<(NN + 255) / 256, 256, 0, stream>>>(partial, zbuf[i & 1], dis, x0, w,
                                                       i, act, zbuf[(i + 1) & 1], out);
    }
}